// Round 2
// baseline (96.528 us; speedup 1.0000x reference)
//
#include <hip/hip_runtime.h>

// PrRoIPool2D(7,7, spatial_scale=0.5), exact integral form.
// features: [8,256,56,56] fp32; rois [R,5]; out [R,256,7,7] fp32.
//
// THIS ROUND: the round-1 XCD-locality experiment (sort + swizzle) was
// falsified (+6.7us). Revised theory: the kernel is bound by cache-LINE
// traffic volume of scattered NCHW reads (~58B useful per 2-3 lines per
// (roi,ch,row); 16 channels of a chunk share no lines). Fix = layout:
//   kernel 1: transpose F -> T[(b*16+chunk)][H][W][16c] in d_ws (25.7MB).
//             Dense lines: one 64B line = 16 channels of one (h,w).
//   kernel 2: block=(roi,chunk): per row, stage the contiguous
//             (span x 16ch) segment with 64-lane float4 loads (1KB/instr)
//             into LDS; x-contract from LDS (lane=(cc,q), 2 tasks);
//             one barrier; y-contract from LDS xint; coalesced stores.
// Feature line traffic ~268MB -> ~70MB.

#define POOLED 7
#define NHMAX 24   // nh = ceil(y1+6bh-1)-ceil(y1-1)+6 <= ceil(6*2.98)+6 = 24
#define SPAN 28    // w-span: ceil(6*bw)+8 <= 26; o0 clamped to W-28

__device__ __forceinline__ float Gfun(float t) {
    return (t <= 0.f) ? 0.5f * (t + 1.f) * (t + 1.f)
                      : 1.f - 0.5f * (1.f - t) * (1.f - t);
}
__device__ __forceinline__ float tent_int(float s, float e, float i) {
    float a = fminf(fmaxf(s - i, -1.f), 1.f);
    float b = fminf(fmaxf(e - i, -1.f), 1.f);
    return Gfun(b) - Gfun(a);
}

// F[N,C,H,W] -> T[cg][H][W][16], cg = b*(C/16)+chunk.
// Block = (cg, 1/8 of rows). Thread (cc=t&15, wi=t>>4): reads float4 (4 w's
// of one channel, coalesced per 64B line), writes 4 scalars; per store
// instruction a wave covers 4 fully-used 64B lines.
__global__ __launch_bounds__(256)
void prroi_transpose(const float* __restrict__ F, float* __restrict__ T,
                     int C, int H, int W) {
    const int bid = blockIdx.x;          // N*(C/16)*8 blocks
    const int hg  = bid & 7;
    const int cg  = bid >> 3;
    const int h0  = hg * (H >> 3);       // 7 rows per block (H=56)
    const int t   = threadIdx.x;
    const int cc  = t & 15, wi = t >> 4;
    const int w0  = wi * 4;
    if (w0 >= W) return;
    const size_t HW = (size_t)H * W;
    const float* Fb = F + ((size_t)cg * 16 + cc) * HW;   // channel plane
    float*       Tb = T + (size_t)cg * HW * 16 + cc;
    float4 v[7];
    #pragma unroll
    for (int i = 0; i < 7; ++i)
        v[i] = *(const float4*)(Fb + (size_t)(h0 + i) * W + w0);
    #pragma unroll
    for (int i = 0; i < 7; ++i) {
        float* p = Tb + ((size_t)(h0 + i) * W + w0) * 16;
        p[0] = v[i].x; p[16] = v[i].y; p[32] = v[i].z; p[48] = v[i].w;
    }
}

__global__ __launch_bounds__(256, 6)
void prroi_main(const float* __restrict__ T, const float* __restrict__ rois,
                float* __restrict__ out, int C, int H, int W) {
    const int blk   = blockIdx.x;
    const int r     = blk >> 4;
    const int chunk = blk & 15;
    const int tid   = threadIdx.x;
    const int wave  = tid >> 6, lane = tid & 63;

    __shared__ float s_wx[7][8];
    __shared__ float s_wy[7][6];
    __shared__ float s_row[4][SPAN][16];      // per-wave row stage (7KB)
    __shared__ float s_xint[NHMAX][16][9];    // [row][cc][q], 9 kills cc*8 bank alias

    const float* roi = rois + (size_t)r * 5;
    const int   b  = (int)roi[0];
    const float x1 = roi[1] * 0.5f, y1 = roi[2] * 0.5f;
    const float x2 = roi[3] * 0.5f, y2 = roi[4] * 0.5f;
    const float bw = (x2 - x1) * (1.f / POOLED);
    const float bh = (y2 - y1) * (1.f / POOLED);
    const float area = bw * bh;
    const float inv_area = (area > 0.f) ? 1.f / fmaxf(area, 1e-12f) : 0.f;

    // ---- weight setup: every wave writes identical values (benign dup, no barrier)
    {
        const int q = lane >> 3, k = lane & 7;
        const int qc = min(q, 6);
        float sx = x1 + qc * bw, ex = sx + bw;
        int oq = min(max((int)ceilf(sx - 1.f), 0), W - 8);
        float wv = tent_int(sx, ex, (float)(oq + k));
        if (q < 7) s_wx[q][k] = wv;
        float sy = y1 + qc * bh, ey = sy + bh;
        int oy = min(max((int)ceilf(sy - 1.f), 0), H - 6);
        float wyv = tent_int(sy, ey, (float)(oy + k)) * inv_area;
        if (q < 7 && k < 6) s_wy[q][k] = wyv;
    }

    const int hb = min(max((int)ceilf(y1 - 1.f), 0), H - 6);
    const int nh = min(max((int)ceilf(y1 + 6.f * bh - 1.f), 0), H - 6) + 6 - hb;
    const int o0 = min(max((int)ceilf(x1 - 1.f), 0), W - SPAN);
    const int o6 = min(max((int)ceilf(x1 + 6.f * bw - 1.f), 0), W - 8);
    const int span16 = (o6 + 8 - o0) * 16;    // dwords to stage per row (<=448)

    // ---- pass1 lane tasks: (cc, qA) and (cc, qA+4)
    const int cc  = lane & 15;
    const int qA  = lane >> 4;                // 0..3
    const int qB  = qA + 4;                   // 4..7 (7 = idle)
    const int qBc = min(qB, 6);
    const int shqA = min(max((int)ceilf(x1 + qA  * bw - 1.f), 0), W - 8) - o0;
    const int shqB = min(max((int)ceilf(x1 + qBc * bw - 1.f), 0), W - 8) - o0;

    float wxA[8], wxB[8];
    #pragma unroll
    for (int k = 0; k < 8; ++k) { wxA[k] = s_wx[qA][k]; wxB[k] = s_wx[qBc][k]; }

    const size_t HW = (size_t)H * W;
    const float* TB = T + (size_t)(b * 16 + chunk) * HW * 16;

    // ---- pass1: wave v handles rows v, v+4, ... ; stage row -> LDS -> x-dot
    for (int row = wave; row < nh; row += 4) {
        const float* src = TB + ((size_t)(hb + row) * W + o0) * 16;
        const int d0 = lane * 4, d1 = 256 + lane * 4;
        const bool m0 = d0 < span16, m1 = d1 < span16;
        float4 v0, v1;
        if (m0) v0 = *(const float4*)(src + d0);
        if (m1) v1 = *(const float4*)(src + d1);
        if (m0) ((float4*)s_row[wave])[lane]      = v0;
        if (m1) ((float4*)s_row[wave])[lane + 64] = v1;   // m1 => lane<48, idx<=111 ok

        float a = 0.f;
        #pragma unroll
        for (int k = 0; k < 8; ++k) a += wxA[k] * s_row[wave][shqA + k][cc];
        s_xint[row][cc][qA] = a;
        if (qB < 7) {
            float a2 = 0.f;
            #pragma unroll
            for (int k = 0; k < 8; ++k) a2 += wxB[k] * s_row[wave][shqB + k][cc];
            s_xint[row][cc][qB] = a2;
        }
    }
    __syncthreads();

    // ---- pass2: 784 outputs (16cc x 7p x 7q), 4 per thread, coalesced stores
    #pragma unroll
    for (int j = 0; j < 4; ++j) {
        const int o = tid + 256 * j;
        if (o < 784) {
            const int cc2 = o / 49;
            const int rem = o - cc2 * 49;
            const int p   = rem / 7;
            const int q   = rem - p * 7;
            const int yo  = min(max((int)ceilf(y1 + p * bh - 1.f), 0), H - 6) - hb;
            float aA = 0.f, aB = 0.f;
            #pragma unroll
            for (int ky = 0; ky < 6; ky += 2) {
                aA += s_wy[p][ky]     * s_xint[yo + ky][cc2][q];
                aB += s_wy[p][ky + 1] * s_xint[yo + ky + 1][cc2][q];
            }
            out[((size_t)r * C + chunk * 16 + cc2) * 49 + rem] = aA + aB;
        }
    }
}

extern "C" void kernel_launch(void* const* d_in, const int* in_sizes, int n_in,
                              void* d_out, int out_size, void* d_ws, size_t ws_size,
                              hipStream_t stream) {
    const float* F    = (const float*)d_in[0];
    const float* rois = (const float*)d_in[1];
    float* out = (float*)d_out;

    const int N = 8, C = 256, H = 56, W = 56;
    const int R = in_sizes[1] / 5;

    float* T = (float*)d_ws;   // 8*16 planes * 56*56*16 floats = 25.7MB < ws
    prroi_transpose<<<N * (C / 16) * 8, 256, 0, stream>>>(F, T, C, H, W);
    prroi_main<<<R * 16, 256, 0, stream>>>(T, rois, out, C, H, W);
}

// Round 3
// 82.926 us; speedup vs baseline: 1.1640x; 1.1640x over previous
//
#include <hip/hip_runtime.h>

// PrRoIPool2D(7,7, spatial_scale=0.5), exact integral form, single-kernel NCHW.
// features: [8,256,56,56] fp32; rois [R,5]; out [R,256,7,7] fp32.
//
// Proven R0 inner structure (82.1us), with CHUNK MERGING this round:
// R1 (XCD locality) and R2 (dense-line transposed layout) were both
// falsified -> kernel time is insensitive to global-memory pattern. The
// surviving theory is per-block fixed cost: 4096 short blocks each paying
// roi load + weight setup (identical across the 16 chunk-blocks of a ROI)
// + launch/drain. Fix: block = (roi, 4-chunk group) -> 1024 blocks; each
// block computes weights ONCE and loops 4 chunks (64 channels). Inner
// per-chunk body is byte-identical to R0. launch_bounds 6->4 removes any
// VGPR-cap spill risk (cap 128 instead of ~85).
//
// Per-chunk body: 4 waves, wave streams its 4 channels FULLY INTERLEAVED:
//   pass1 (lanes q=lane&7, hs=lane>>3): xint[ch][hh][q] = dot8(wx[q], Frow)
//          2x float4 16B-aligned loads per channel, all 4 channels per row-iter
//   pass2 (lanes p=lane>>3, q=lane&7): out = sum_ky wy[p][ky]*xint[ch][yo_p+ky][q]
// Barrier-free: all LDS produce->consume within-wave; chunk iterations are
// ordered within-wave via lgkmcnt (compiler-inserted), no __syncthreads.

#define POOLED 7
#define NHMAX 24   // y window rows: 7*bh+2 <= 22.9 for this problem's bh<=2.98
#define XS 9       // xint row stride (odd -> spreads banks; slot 7 = pad)

__device__ __forceinline__ float Gfun(float t) {
    return (t <= 0.f) ? 0.5f * (t + 1.f) * (t + 1.f)
                      : 1.f - 0.5f * (1.f - t) * (1.f - t);
}
__device__ __forceinline__ float tent_int(float s, float e, float i) {
    float a = fminf(fmaxf(s - i, -1.f), 1.f);
    float b = fminf(fmaxf(e - i, -1.f), 1.f);
    return Gfun(b) - Gfun(a);
}

__global__ __launch_bounds__(256, 4)
void prroi_kernel(const float* __restrict__ F, const float* __restrict__ rois,
                  float* __restrict__ out, int C, int H, int W) {
    const int blk  = blockIdx.x;
    const int r    = blk >> 2;           // 4 blocks per roi
    const int cg   = blk & 3;            // chunk group: chunks cg*4 .. cg*4+3
    const int wave = threadIdx.x >> 6;
    const int lane = threadIdx.x & 63;

    __shared__ float s_wx[4][7][8];
    __shared__ float s_wy[4][7][6];
    __shared__ float s_xint[4][4][NHMAX][XS];   // [wave][ch][row][q]

    const float* roi = rois + (size_t)r * 5;
    const int   b  = (int)roi[0];
    const float x1 = roi[1] * 0.5f, y1 = roi[2] * 0.5f;
    const float x2 = roi[3] * 0.5f, y2 = roi[4] * 0.5f;
    const float bw = (x2 - x1) * (1.f / POOLED);
    const float bh = (y2 - y1) * (1.f / POOLED);
    const float area = bw * bh;
    const float inv_area = (area > 0.f) ? 1.f / fmaxf(area, 1e-12f) : 0.f;

    // ---- branch-free weight setup, ONCE per block (chunk-independent):
    // lane -> task (q = lane>>3, k = lane&7), masked stores
    {
        const int q = lane >> 3, k = lane & 7;
        float sx = x1 + q * bw, ex = sx + bw;
        int o = min(max(((int)ceilf(sx - 1.f)) & ~3, 0), W - 8);   // 16B aligned
        float wv = tent_int(sx, ex, (float)(o + k));
        if (q < 7) s_wx[wave][q][k] = wv;
        float sy = y1 + q * bh, ey = sy + bh;
        int oy = min(max((int)ceilf(sy - 1.f), 0), H - 6);
        float wyv = tent_int(sy, ey, (float)(oy + k)) * inv_area;
        if (q < 7 && k < 6) s_wy[wave][q][k] = wyv;
    }

    // ---- per-lane state, computed directly (no LDS round-trip for scalars)
    const int q1 = lane & 7, hs = lane >> 3;
    const int qq = min(q1, 6);
    const int ox1 = min(max(((int)ceilf(x1 + qq * bw - 1.f)) & ~3, 0), W - 8);
    float wx1[8];
    #pragma unroll
    for (int k = 0; k < 8; ++k) wx1[k] = s_wx[wave][qq][k];   // 2x ds_read_b128

    const int p2 = lane >> 3, q2 = lane & 7;
    const int pp = min(p2, 6);
    const int hb  = min(max((int)ceilf(y1 - 1.f), 0), H - 6);
    const int oy6 = min(max((int)ceilf(y1 + 6.f * bh - 1.f), 0), H - 6);
    const int nh  = oy6 + 6 - hb;                 // wave-uniform, <= NHMAX
    const int yo2 = min(max((int)ceilf(y1 + pp * bh - 1.f), 0), H - 6) - hb;
    float wy2[6];
    #pragma unroll
    for (int k = 0; k < 6; ++k) wy2[k] = s_wy[wave][pp][k];

    const size_t HW = (size_t)H * W;
    const int itcnt = (nh + 7) >> 3;              // 1..3, wave-uniform
    const bool st = (lane < 56) && (q2 < 7);

    // ---- chunk loop: 4 chunks of 16 channels, weights reused
    #pragma unroll 1
    for (int ci = 0; ci < 4; ++ci) {
        const int chunk = cg * 4 + ci;
        const int c0 = chunk * 16 + wave * 4;
        const float* Fc0 = F + ((size_t)b * C + c0) * HW;

        // pass1: all 4 channels interleaved per row-iteration
        for (int it = 0; it < itcnt; ++it) {
            const int hh = it * 8 + hs;
            if (hh < nh && q1 < 7) {
                const float* rowb = Fc0 + (size_t)(hb + hh) * W + ox1;
                #pragma unroll
                for (int ch = 0; ch < 4; ++ch) {
                    const float4* rp = (const float4*)(rowb + ch * HW);
                    float4 v0 = rp[0], v1 = rp[1];    // 4 independent chains/lane
                    float sA = wx1[0] * v0.x + wx1[1] * v0.y + wx1[2] * v0.z + wx1[3] * v0.w;
                    float sB = wx1[4] * v1.x + wx1[5] * v1.y + wx1[6] * v1.z + wx1[7] * v1.w;
                    s_xint[wave][ch][hh][q1] = sA + sB;
                }
            }
        }

        // pass2: 6-tap y-contraction per channel, split accumulator chains
        #pragma unroll
        for (int ch = 0; ch < 4; ++ch) {
            float aA = 0.f, aB = 0.f;
            #pragma unroll
            for (int ky = 0; ky < 6; ky += 2) {
                aA += wy2[ky]     * s_xint[wave][ch][yo2 + ky][q2];
                aB += wy2[ky + 1] * s_xint[wave][ch][yo2 + ky + 1][q2];
            }
            if (st)
                out[((size_t)r * C + c0 + ch) * 49 + p2 * 7 + q2] = aA + aB;
        }
    }
}

extern "C" void kernel_launch(void* const* d_in, const int* in_sizes, int n_in,
                              void* d_out, int out_size, void* d_ws, size_t ws_size,
                              hipStream_t stream) {
    const float* F    = (const float*)d_in[0];
    const float* rois = (const float*)d_in[1];
    float* out = (float*)d_out;

    const int C = 256, H = 56, W = 56;
    const int R = in_sizes[1] / 5;
    prroi_kernel<<<R * 4, 256, 0, stream>>>(F, rois, out, C, H, W);
}